// Round 1
// baseline (47.177 us; speedup 1.0000x reference)
//
#include <hip/hip_runtime.h>

// Output = piecewise(x).T  (the reference's matmul is dead code / DCE'd).
// x: [8192, 4096] f32 row-major  ->  out: [4096, 8192] f32 row-major.
//
// Piecewise semantics (searchsorted left, minus 1, clipped to [0,4]):
//   v <  -2            -> 0
//   -2 <= v <= -1      -> poly0      (v == -2 edge: idx=0, mask false -> poly0)
//   (-1, 0]            -> poly1
//   ( 0, 1]            -> poly2
//   ( 1, 2]            -> poly3
//   v >  2             -> poly4

__device__ __forceinline__ float pw_eval(float v) {
    const bool g0 = v > -1.0f;
    const bool g1 = v > 0.0f;
    const bool g2 = v > 1.0f;
    const bool g3 = v > 2.0f;
    // COEFFS rows: idx 0..4, columns c0..c3
    const float c0 = g1 ? (g2 ? (g3 ? 1.0f  : -0.2f) : 0.3f ) : (g0 ? 0.0f  : 0.5f );
    const float c1 = g1 ? (g2 ? (g3 ? -0.3f :  0.4f) : 0.7f ) : (g0 ? 1.0f  : -1.0f);
    const float c2 = g1 ? (g2 ? (g3 ? 0.2f  :  0.6f) : 0.1f ) : (g0 ? -0.5f : 0.25f);
    const float c3 = g1 ? (g2 ? (g3 ? 0.01f :  0.05f) : -0.15f) : (g0 ? 0.2f : 0.10f);
    const float r = fmaf(fmaf(fmaf(c3, v, c2), v, c1), v, c0);
    return (v < -2.0f) ? 0.0f : r;
}

__global__ __launch_bounds__(256) void pw_transpose_kernel(
    const float* __restrict__ x, float* __restrict__ out) {
    constexpr int Bdim = 8192;   // rows of x
    constexpr int Fdim = 4096;   // cols of x
    constexpr int TILE = 64;

    // tile[f_local][b_local]; +1 pad -> bank (f + b) mod 32, 2-way over a wave (free)
    __shared__ float tile[TILE][TILE + 1];

    const int f0 = blockIdx.x * TILE;   // along F (x cols / out rows)
    const int b0 = blockIdx.y * TILE;   // along B (x rows / out cols)
    const int tid = threadIdx.x;
    const int c = tid & 15;             // float4 slot within a 64-wide row
    const int r = tid >> 4;             // 0..15

    // Load 64x64 input tile: coalesced float4 reads along F, apply piecewise,
    // store transposed into LDS.
    #pragma unroll
    for (int p = 0; p < 4; ++p) {
        const int row = r + p * 16;  // b_local
        const float4 v = *reinterpret_cast<const float4*>(
            x + (size_t)(b0 + row) * Fdim + f0 + 4 * c);
        tile[4 * c + 0][row] = pw_eval(v.x);
        tile[4 * c + 1][row] = pw_eval(v.y);
        tile[4 * c + 2][row] = pw_eval(v.z);
        tile[4 * c + 3][row] = pw_eval(v.w);
    }

    __syncthreads();

    // Write out tile: coalesced float4 writes along B.
    #pragma unroll
    for (int p = 0; p < 4; ++p) {
        const int frow = r + p * 16;  // f_local
        float4 o;
        o.x = tile[frow][4 * c + 0];
        o.y = tile[frow][4 * c + 1];
        o.z = tile[frow][4 * c + 2];
        o.w = tile[frow][4 * c + 3];
        *reinterpret_cast<float4*>(
            out + (size_t)(f0 + frow) * Bdim + b0 + 4 * c) = o;
    }
}

extern "C" void kernel_launch(void* const* d_in, const int* in_sizes, int n_in,
                              void* d_out, int out_size, void* d_ws, size_t ws_size,
                              hipStream_t stream) {
    const float* x = (const float*)d_in[0];  // [8192, 4096] f32
    // d_in[1] (w) and d_in[2] (b) are dead in the reference output.
    float* out = (float*)d_out;              // [4096, 8192] f32

    dim3 grid(4096 / 64, 8192 / 64);  // 64 x 128 tiles
    pw_transpose_kernel<<<grid, 256, 0, stream>>>(x, out);
}